// Round 8
// baseline (112.863 us; speedup 1.0000x reference)
//
#include <hip/hip_runtime.h>
#include <hip/hip_bf16.h>
#include <stdint.h>

typedef unsigned short u16;
using bf16x8 = __attribute__((ext_vector_type(8))) short;
using f32x4v = __attribute__((ext_vector_type(4))) float;

#define BATCH 4
#define CDIM 512
#define NQ 1024
#define NKV 2048
#define NH 8
#define HD 64

__device__ __forceinline__ u16 f2bf(float f) {
  uint32_t u = __float_as_uint(f);
  u += 0x7fffu + ((u >> 16) & 1u);
  return (u16)(u >> 16);
}
// compiler-path bf16 cast (pairs fuse to v_cvt_pk_bf16_f32)
__device__ __forceinline__ u16 f2bf_c(float f) {
  __hip_bfloat16 h = __float2bfloat16(f);
  union { __hip_bfloat16 b; u16 u; } cv;
  cv.b = h;
  return cv.u;
}

// ---------------- fp32 -> bf16 convert (weights) ----------------
__global__ void cvt_w(const float* __restrict__ in, u16* __restrict__ out, int n) {
  int i = blockIdx.x * 256 + threadIdx.x;
  if (i < n) out[i] = f2bf(in[i]);
}

// ---------------- (B, C, N) f32 -> (B, N, C) bf16 ----------------
__global__ void pack_cvt(const float* __restrict__ in, u16* __restrict__ out,
                         int C, int N) {
  __shared__ float t[32][33];
  int b = blockIdx.z;
  int n0 = blockIdx.x * 32, c0 = blockIdx.y * 32;
  int tx = threadIdx.x, ty = threadIdx.y;
  const float* ib = in + (size_t)b * C * N;
#pragma unroll
  for (int i = 0; i < 4; ++i)
    t[ty + i * 8][tx] = ib[(size_t)(c0 + ty + i * 8) * N + n0 + tx];
  __syncthreads();
  u16* ob = out + (size_t)b * N * C;
#pragma unroll
  for (int i = 0; i < 4; ++i)
    ob[(size_t)(n0 + ty + i * 8) * C + c0 + tx] = f2bf(t[tx][ty + i * 8]);
}

// ---------------- V slice of khv -> vt[b,h,d,kv] ----------------
__global__ void transpose_vh(const u16* __restrict__ khv, u16* __restrict__ vt) {
  __shared__ u16 t[32][33];
  int bh = blockIdx.z;
  int b = bh >> 3, h = bh & 7;
  int kv0 = blockIdx.x * 32, d0 = blockIdx.y * 32;
  int tx = threadIdx.x, ty = threadIdx.y;
  const u16* ib = khv + (size_t)b * NKV * 1024 + 512 + h * HD;
#pragma unroll
  for (int i = 0; i < 4; ++i)
    t[ty + i * 8][tx] = ib[(size_t)(kv0 + ty + i * 8) * 1024 + d0 + tx];
  __syncthreads();
  u16* ob = vt + (size_t)bh * HD * NKV;
#pragma unroll
  for (int i = 0; i < 4; ++i)
    ob[(size_t)(d0 + ty + i * 8) * NKV + kv0 + tx] = t[tx][ty + i * 8];
}

// ---------------- GEMM: C[m,n] = sum_k A[m,k]*B[n,k] + bias[n] ----------------
// OUTMODE 0: bf16 row-major (ldc). OUTMODE 2: f32 transposed to (B, C, NQ).
template <int OUTMODE>
__global__ __launch_bounds__(256) void gemm_bt(
    const u16* __restrict__ A, const u16* __restrict__ B,
    const float* __restrict__ bias, void* __restrict__ Cout,
    int M, int N, int K, int ldc) {
  __shared__ alignas(16) u16 lsA[2][128 * 32];
  __shared__ alignas(16) u16 lsB[2][128 * 32];
  int t = threadIdx.x, l = t & 63, w = t >> 6;
  int lr = l & 15, lg = l >> 4;
  int wr = w >> 1, wc = w & 1;
  int m0 = blockIdx.x * 128, n0 = blockIdx.y * 128;
  const u16* Ag = A + (size_t)m0 * K;
  const u16* Bg = B + (size_t)n0 * K;
  f32x4v acc[4][4] = {};

  auto stage = [&](int buf, int k0) {
#pragma unroll
    for (int r = 0; r < 2; ++r) {
      int e = (r * 256 + t) * 8;
      int row = e >> 5, col = e & 31;
      __builtin_amdgcn_global_load_lds(
          (const __attribute__((address_space(1))) void*)(Ag + (size_t)row * K + k0 + col),
          (__attribute__((address_space(3))) void*)(&lsA[buf][r * 2048 + w * 512]),
          16, 0, 0);
      __builtin_amdgcn_global_load_lds(
          (const __attribute__((address_space(1))) void*)(Bg + (size_t)row * K + k0 + col),
          (__attribute__((address_space(3))) void*)(&lsB[buf][r * 2048 + w * 512]),
          16, 0, 0);
    }
  };

  stage(0, 0);
  int nk = K >> 5, cur = 0;
  for (int kt = 0; kt < nk; ++kt) {
    __syncthreads();
    if (kt + 1 < nk) stage(cur ^ 1, (kt + 1) << 5);
    const u16* la = lsA[cur];
    const u16* lb = lsB[cur];
    bf16x8 af[4], bfr[4];
#pragma unroll
    for (int m = 0; m < 4; ++m)
      af[m] = *(const bf16x8*)&la[(wr * 64 + m * 16 + lr) * 32 + lg * 8];
#pragma unroll
    for (int n = 0; n < 4; ++n)
      bfr[n] = *(const bf16x8*)&lb[(wc * 64 + n * 16 + lr) * 32 + lg * 8];
#pragma unroll
    for (int m = 0; m < 4; ++m)
#pragma unroll
      for (int n = 0; n < 4; ++n)
        acc[m][n] = __builtin_amdgcn_mfma_f32_16x16x32_bf16(af[m], bfr[n], acc[m][n], 0, 0, 0);
    cur ^= 1;
  }

  // epilogue: C/D layout col=lane&15, row=(lane>>4)*4+j
#pragma unroll
  for (int m = 0; m < 4; ++m) {
    int row = m0 + wr * 64 + m * 16 + lg * 4;
#pragma unroll
    for (int n = 0; n < 4; ++n) {
      int col = n0 + wc * 64 + n * 16 + lr;
      float bv = bias[col];
      if (OUTMODE == 0) {
#pragma unroll
        for (int j = 0; j < 4; ++j)
          ((u16*)Cout)[(size_t)(row + j) * ldc + col] = f2bf(acc[m][n][j] + bv);
      } else {
        // transposed store: token rows row..row+3 -> out[b][col][tok]
        int bb = row >> 10, tok = row & 1023;
        f32x4v v;
#pragma unroll
        for (int j = 0; j < 4; ++j) v[j] = acc[m][n][j] + bv;
        *(f32x4v*)&((float*)Cout)[((size_t)bb * CDIM + col) * NQ + tok] = v;
      }
    }
  }
}

// ---------------- flash attention v4: 2-wave blocks, exp2 softmax ----------
// grid (32 bh, 32 qtiles), block 128 = 2 waves, 16 q-rows/wave, KVBLK=64.
// 1024 blocks -> 4 blocks/CU: 4 independent barrier domains hide the
// vmcnt-drain stalls. S^T = mfma(K,Q): lane-local softmax (15 fmax + 2 shfl).
// Softmax in exp2 domain: p = exp2(fma(s, scale*log2e, -m2)).
__global__ __launch_bounds__(128) void attn_fwd(
    const u16* __restrict__ qh,   // (B*NQ, 512)
    const u16* __restrict__ khv,  // (B*NKV, 1024): cols 0..511 = K
    const u16* __restrict__ vt,   // (B*8*64, NKV)
    u16* __restrict__ ao) {       // (B*NQ, 512)
  __shared__ alignas(16) u16 lsK[2][64 * 64];
  __shared__ alignas(16) u16 lsV[2][64 * 64];
  __shared__ alignas(16) u16 plds[2][16 * 64];
  const float scale2 = 0.125f * 1.44269504089f;  // scale * log2(e)
  int t = threadIdx.x, l = t & 63, w = t >> 6;
  int lr = l & 15, lg = l >> 4;
  int bh = blockIdx.x, b = bh >> 3, h = bh & 7;
  int q0 = blockIdx.y * 32 + w * 16;
  const u16* Qb = qh + ((size_t)b * NQ + q0) * 512 + h * HD;
  const u16* Kb = khv + (size_t)b * NKV * 1024 + h * HD;
  const u16* Vtb = vt + (size_t)bh * HD * NKV;

  int srow = w * 8 + (l >> 3);   // 0..15: base tile row this lane stages
  int c16 = l & 7;               // 16B-block index within 128B row

  auto stageK = [&](int buf, int kv0) {
#pragma unroll
    for (int i = 0; i < 4; ++i) {
      int row = srow + i * 16;
      int sc = c16 ^ (row & 7);  // inverse-swizzled source block
      __builtin_amdgcn_global_load_lds(
          (const __attribute__((address_space(1))) void*)(Kb + (size_t)(kv0 + row) * 1024 + sc * 8),
          (__attribute__((address_space(3))) void*)(&lsK[buf][w * 512 + i * 1024]),
          16, 0, 0);
    }
  };
  auto stageV = [&](int buf, int kv0) {
#pragma unroll
    for (int i = 0; i < 4; ++i) {
      int row = srow + i * 16;   // d index
      int sc = c16 ^ (row & 7);
      __builtin_amdgcn_global_load_lds(
          (const __attribute__((address_space(1))) void*)(Vtb + (size_t)row * NKV + kv0 + sc * 8),
          (__attribute__((address_space(3))) void*)(&lsV[buf][w * 512 + i * 1024]),
          16, 0, 0);
    }
  };

  bf16x8 qa[2];
#pragma unroll
  for (int s = 0; s < 2; ++s)
    qa[s] = *(const bf16x8*)(Qb + (size_t)lr * 512 + s * 32 + lg * 8);

  float m2 = -INFINITY;     // running max (log2 domain) for q row = q0+lr
  float lrow = 0.f;         // running denom
  f32x4v od[4] = {};        // O^T: od[n][j] -> d = n*16+lg*4+j, q = lr

  char* pwave = (char*)&plds[w][0];
  int swz = (lr & 7) << 4;

  stageK(0, 0);
  stageV(0, 0);
  int cur = 0;
  const int NT = NKV / 64;
  for (int kt = 0; kt < NT; ++kt) {
    __syncthreads();                     // vmcnt drained -> buf[cur] ready
    if (kt + 1 < NT) { stageK(cur ^ 1, (kt + 1) * 64); stageV(cur ^ 1, (kt + 1) * 64); }

    // S^T = K Q^T: A = K-frag, B = Q-frag
    f32x4v sfr[4] = {};
#pragma unroll
    for (int sk = 0; sk < 2; ++sk)
#pragma unroll
      for (int n = 0; n < 4; ++n) {
        bf16x8 kb = *(const bf16x8*)&lsK[cur][(n * 16 + lr) * 64 + ((sk * 4 + lg) ^ (lr & 7)) * 8];
        sfr[n] = __builtin_amdgcn_mfma_f32_16x16x32_bf16(kb, qa[sk], sfr[n], 0, 0, 0);
      }

    // lane-local max over 16 kv values (log2 domain)
    float pm = fmaxf(fmaxf(fmaxf(sfr[0][0], sfr[0][1]), fmaxf(sfr[0][2], sfr[0][3])),
                     fmaxf(fmaxf(sfr[1][0], sfr[1][1]), fmaxf(sfr[1][2], sfr[1][3])));
    float pm2 = fmaxf(fmaxf(fmaxf(sfr[2][0], sfr[2][1]), fmaxf(sfr[2][2], sfr[2][3])),
                      fmaxf(fmaxf(sfr[3][0], sfr[3][1]), fmaxf(sfr[3][2], sfr[3][3])));
    pm = fmaxf(pm, pm2) * scale2;
    pm = fmaxf(pm, __shfl_xor(pm, 16, 64));
    pm = fmaxf(pm, __shfl_xor(pm, 32, 64));

    // exact-skip rescale
    if (__any(pm > m2)) {
      float mn = fmaxf(m2, pm);
      float alpha = __builtin_amdgcn_exp2f(m2 - mn);
      m2 = mn;
      lrow *= alpha;
#pragma unroll
      for (int n = 0; n < 4; ++n)
#pragma unroll
        for (int j = 0; j < 4; ++j)
          od[n][j] *= alpha;
    }

    float p[4][4];
    float rs = 0.f;
#pragma unroll
    for (int n = 0; n < 4; ++n)
#pragma unroll
      for (int j = 0; j < 4; ++j) {
        float e = __builtin_amdgcn_exp2f(fmaf(sfr[n][j], scale2, -m2));
        p[n][j] = e;
        rs += e;
      }
    rs += __shfl_xor(rs, 16, 64);
    rs += __shfl_xor(rs, 32, 64);
    lrow += rs;

    // P[q=lr][kv] -> LDS, 4x ds_write_b64, swizzled (cvt_pk pairs)
#pragma unroll
    for (int n = 0; n < 4; ++n) {
      ushort4 pw;
      pw.x = f2bf_c(p[n][0]); pw.y = f2bf_c(p[n][1]);
      pw.z = f2bf_c(p[n][2]); pw.w = f2bf_c(p[n][3]);
      *(ushort4*)(pwave + lr * 128 + ((n * 32 + lg * 8) ^ swz)) = pw;
    }

    // O^T += V^T P^T: A = V^T-frag, B = P^T from plds
#pragma unroll
    for (int sk = 0; sk < 2; ++sk) {
      bf16x8 pa = *(const bf16x8*)(pwave + lr * 128 + ((sk * 64 + lg * 16) ^ swz));
#pragma unroll
      for (int n = 0; n < 4; ++n) {
        bf16x8 vb = *(const bf16x8*)&lsV[cur][(n * 16 + lr) * 64 + ((sk * 4 + lg) ^ (lr & 7)) * 8];
        od[n] = __builtin_amdgcn_mfma_f32_16x16x32_bf16(vb, pa, od[n], 0, 0, 0);
      }
    }
    cur ^= 1;
  }

  float rl = 1.0f / lrow;
  u16* aob = ao + ((size_t)b * NQ + q0 + lr) * 512 + h * HD + lg * 4;
#pragma unroll
  for (int n = 0; n < 4; ++n) {
    ushort4 o;
    o.x = f2bf_c(od[n][0] * rl); o.y = f2bf_c(od[n][1] * rl);
    o.z = f2bf_c(od[n][2] * rl); o.w = f2bf_c(od[n][3] * rl);
    *(ushort4*)(aob + n * 16) = o;
  }
}

// ---------------- launch ----------------
extern "C" void kernel_launch(void* const* d_in, const int* in_sizes, int n_in,
                              void* d_out, int out_size, void* d_ws, size_t ws_size,
                              hipStream_t stream) {
  const float* q    = (const float*)d_in[0];
  const float* kv   = (const float*)d_in[1];
  const float* Wqkv = (const float*)d_in[2];
  const float* bqkv = (const float*)d_in[3];
  const float* Wout = (const float*)d_in[4];
  const float* bout = (const float*)d_in[5];
  float* out = (float*)d_out;
  uint8_t* ws = (uint8_t*)d_ws;

  u16* qf  = (u16*)(ws + 0);            // 4 MB  (B*NQ, 512) bf16
  u16* kvf = (u16*)(ws + (4u << 20));   // 8 MB  (B*NKV, 512) bf16
  u16* wq  = (u16*)(ws + (12u << 20));  // 1.5MB Wqkv bf16 (1536,512)
  u16* wo  = (u16*)(ws + (14u << 20));  // 0.5MB Wout bf16 (512,512)
  u16* qhb = (u16*)(ws + (15u << 20));  // 4 MB  (B*NQ, 512)
  u16* khv = (u16*)(ws + (19u << 20));  // 16 MB (B*NKV, 1024) K|V
  u16* vt  = (u16*)(ws + (35u << 20));  // 8 MB  (B*8*64, NKV)
  u16* ao  = (u16*)(ws + (43u << 20));  // 4 MB  (B*NQ, 512)

  dim3 blk256(256), blkT(32, 8);

  cvt_w<<<dim3((1536 * 512 + 255) / 256), blk256, 0, stream>>>(Wqkv, wq, 1536 * 512);
  cvt_w<<<dim3((512 * 512 + 255) / 256), blk256, 0, stream>>>(Wout, wo, 512 * 512);
  pack_cvt<<<dim3(NQ / 32, CDIM / 32, BATCH), blkT, 0, stream>>>(q, qf, CDIM, NQ);
  pack_cvt<<<dim3(NKV / 32, CDIM / 32, BATCH), blkT, 0, stream>>>(kv, kvf, CDIM, NKV);

  gemm_bt<0><<<dim3(BATCH * NQ / 128, 512 / 128), blk256, 0, stream>>>(
      qf, wq, bqkv, qhb, BATCH * NQ, 512, 512, 512);
  gemm_bt<0><<<dim3(BATCH * NKV / 128, 1024 / 128), blk256, 0, stream>>>(
      kvf, wq + 512 * 512, bqkv + 512, khv, BATCH * NKV, 1024, 512, 1024);

  transpose_vh<<<dim3(NKV / 32, HD / 32, BATCH * NH), blkT, 0, stream>>>(khv, vt);

  attn_fwd<<<dim3(BATCH * NH, NQ / 32), dim3(128), 0, stream>>>(qhb, khv, vt, ao);

  // out projection fused with NHWC->NCHW transpose, writes d_out directly
  gemm_bt<2><<<dim3(BATCH * NQ / 128, 512 / 128), blk256, 0, stream>>>(
      ao, wo, bout, out, BATCH * NQ, 512, 512, 512);
}

// Round 10
// 108.192 us; speedup vs baseline: 1.0432x; 1.0432x over previous
//
#include <hip/hip_runtime.h>
#include <hip/hip_bf16.h>
#include <stdint.h>

typedef unsigned short u16;
using bf16x8 = __attribute__((ext_vector_type(8))) short;
using f32x4v = __attribute__((ext_vector_type(4))) float;

#define BATCH 4
#define CDIM 512
#define NQ 1024
#define NKV 2048
#define NH 8
#define HD 64

__device__ __forceinline__ u16 f2bf(float f) {
  uint32_t u = __float_as_uint(f);
  u += 0x7fffu + ((u >> 16) & 1u);
  return (u16)(u >> 16);
}
// compiler-path bf16 cast (pairs fuse to v_cvt_pk_bf16_f32)
__device__ __forceinline__ u16 f2bf_c(float f) {
  __hip_bfloat16 h = __float2bfloat16(f);
  union { __hip_bfloat16 b; u16 u; } cv;
  cv.b = h;
  return cv.u;
}

// ---------------- fp32 -> bf16 convert (weights) ----------------
__global__ void cvt_w(const float* __restrict__ in, u16* __restrict__ out, int n) {
  int i = blockIdx.x * 256 + threadIdx.x;
  if (i < n) out[i] = f2bf(in[i]);
}

// ---------------- (B, C, N) f32 -> (B, N, C) bf16 ----------------
__global__ void pack_cvt(const float* __restrict__ in, u16* __restrict__ out,
                         int C, int N) {
  __shared__ float t[32][33];
  int b = blockIdx.z;
  int n0 = blockIdx.x * 32, c0 = blockIdx.y * 32;
  int tx = threadIdx.x, ty = threadIdx.y;
  const float* ib = in + (size_t)b * C * N;
#pragma unroll
  for (int i = 0; i < 4; ++i)
    t[ty + i * 8][tx] = ib[(size_t)(c0 + ty + i * 8) * N + n0 + tx];
  __syncthreads();
  u16* ob = out + (size_t)b * N * C;
#pragma unroll
  for (int i = 0; i < 4; ++i)
    ob[(size_t)(n0 + ty + i * 8) * C + c0 + tx] = f2bf(t[tx][ty + i * 8]);
}

// ---------------- V slice of khv -> vt[b,h,d,kv] ----------------
__global__ void transpose_vh(const u16* __restrict__ khv, u16* __restrict__ vt) {
  __shared__ u16 t[32][33];
  int bh = blockIdx.z;
  int b = bh >> 3, h = bh & 7;
  int kv0 = blockIdx.x * 32, d0 = blockIdx.y * 32;
  int tx = threadIdx.x, ty = threadIdx.y;
  const u16* ib = khv + (size_t)b * NKV * 1024 + 512 + h * HD;
#pragma unroll
  for (int i = 0; i < 4; ++i)
    t[ty + i * 8][tx] = ib[(size_t)(kv0 + ty + i * 8) * 1024 + d0 + tx];
  __syncthreads();
  u16* ob = vt + (size_t)bh * HD * NKV;
#pragma unroll
  for (int i = 0; i < 4; ++i)
    ob[(size_t)(d0 + ty + i * 8) * NKV + kv0 + tx] = t[tx][ty + i * 8];
}

// ---------------- GEMM: C[m,n] = sum_k A[m,k]*B[n,k] + bias[n] ----------------
// OUTMODE 0: bf16 row-major (ldc). OUTMODE 2: f32 transposed to (B, C, NQ).
template <int OUTMODE>
__global__ __launch_bounds__(256) void gemm_bt(
    const u16* __restrict__ A, const u16* __restrict__ B,
    const float* __restrict__ bias, void* __restrict__ Cout,
    int M, int N, int K, int ldc) {
  __shared__ alignas(16) u16 lsA[2][128 * 32];
  __shared__ alignas(16) u16 lsB[2][128 * 32];
  int t = threadIdx.x, l = t & 63, w = t >> 6;
  int lr = l & 15, lg = l >> 4;
  int wr = w >> 1, wc = w & 1;
  int m0 = blockIdx.x * 128, n0 = blockIdx.y * 128;
  const u16* Ag = A + (size_t)m0 * K;
  const u16* Bg = B + (size_t)n0 * K;
  f32x4v acc[4][4] = {};

  auto stage = [&](int buf, int k0) {
#pragma unroll
    for (int r = 0; r < 2; ++r) {
      int e = (r * 256 + t) * 8;
      int row = e >> 5, col = e & 31;
      __builtin_amdgcn_global_load_lds(
          (const __attribute__((address_space(1))) void*)(Ag + (size_t)row * K + k0 + col),
          (__attribute__((address_space(3))) void*)(&lsA[buf][r * 2048 + w * 512]),
          16, 0, 0);
      __builtin_amdgcn_global_load_lds(
          (const __attribute__((address_space(1))) void*)(Bg + (size_t)row * K + k0 + col),
          (__attribute__((address_space(3))) void*)(&lsB[buf][r * 2048 + w * 512]),
          16, 0, 0);
    }
  };

  stage(0, 0);
  int nk = K >> 5, cur = 0;
  for (int kt = 0; kt < nk; ++kt) {
    __syncthreads();
    if (kt + 1 < nk) stage(cur ^ 1, (kt + 1) << 5);
    const u16* la = lsA[cur];
    const u16* lb = lsB[cur];
    bf16x8 af[4], bfr[4];
#pragma unroll
    for (int m = 0; m < 4; ++m)
      af[m] = *(const bf16x8*)&la[(wr * 64 + m * 16 + lr) * 32 + lg * 8];
#pragma unroll
    for (int n = 0; n < 4; ++n)
      bfr[n] = *(const bf16x8*)&lb[(wc * 64 + n * 16 + lr) * 32 + lg * 8];
#pragma unroll
    for (int m = 0; m < 4; ++m)
#pragma unroll
      for (int n = 0; n < 4; ++n)
        acc[m][n] = __builtin_amdgcn_mfma_f32_16x16x32_bf16(af[m], bfr[n], acc[m][n], 0, 0, 0);
    cur ^= 1;
  }

  // epilogue: C/D layout col=lane&15, row=(lane>>4)*4+j
#pragma unroll
  for (int m = 0; m < 4; ++m) {
    int row = m0 + wr * 64 + m * 16 + lg * 4;
#pragma unroll
    for (int n = 0; n < 4; ++n) {
      int col = n0 + wc * 64 + n * 16 + lr;
      float bv = bias[col];
      if (OUTMODE == 0) {
#pragma unroll
        for (int j = 0; j < 4; ++j)
          ((u16*)Cout)[(size_t)(row + j) * ldc + col] = f2bf(acc[m][n][j] + bv);
      } else {
        // transposed store: token rows row..row+3 -> out[b][col][tok]
        int bb = row >> 10, tok = row & 1023;
        f32x4v v;
#pragma unroll
        for (int j = 0; j < 4; ++j) v[j] = acc[m][n][j] + bv;
        *(f32x4v*)&((float*)Cout)[((size_t)bb * CDIM + col) * NQ + tok] = v;
      }
    }
  }
}

// ---------------- flash attention v5: triple-buffer + counted vmcnt -------
// grid (32 bh, 16 qtiles), block 256 = 4 waves, 16 q-rows/wave, KVBLK=64.
// S^T = mfma(K,Q): lane-local softmax (exp2 domain). P via 4x ds_write_b64.
// Sync: raw s_barrier with s_waitcnt vmcnt(4) (t's loads done, t+1's stay in
// flight); stage(t+2) issued after the barrier into buf[(t+2)%3] (last read
// at tile t-1, so no race). Loads get ~2 compute phases to land -> no drain.
__global__ __launch_bounds__(256) void attn_fwd(
    const u16* __restrict__ qh,   // (B*NQ, 512)
    const u16* __restrict__ khv,  // (B*NKV, 1024): cols 0..511 = K
    const u16* __restrict__ vt,   // (B*8*64, NKV)
    u16* __restrict__ ao) {       // (B*NQ, 512)
  __shared__ alignas(16) u16 lsK[3][64 * 64];
  __shared__ alignas(16) u16 lsV[3][64 * 64];
  __shared__ alignas(16) u16 plds[4][16 * 64];
  const float scale2 = 0.125f * 1.44269504089f;  // scale * log2(e)
  int t = threadIdx.x, l = t & 63, w = t >> 6;
  int lr = l & 15, lg = l >> 4;
  int bh = blockIdx.x, b = bh >> 3, h = bh & 7;
  int q0 = blockIdx.y * 64 + w * 16;
  const u16* Qb = qh + ((size_t)b * NQ + q0) * 512 + h * HD;
  const u16* Kb = khv + (size_t)b * NKV * 1024 + h * HD;
  const u16* Vtb = vt + (size_t)bh * HD * NKV;

  int srow = w * 8 + (l >> 3);   // 0..31: tile row this lane stages
  int c16 = l & 7;               // 16B-block index within 128B row

  auto stageK = [&](int buf, int kv0) {
#pragma unroll
    for (int i = 0; i < 2; ++i) {
      int row = srow + i * 32;
      int sc = c16 ^ (row & 7);  // inverse-swizzled source block
      __builtin_amdgcn_global_load_lds(
          (const __attribute__((address_space(1))) void*)(Kb + (size_t)(kv0 + row) * 1024 + sc * 8),
          (__attribute__((address_space(3))) void*)(&lsK[buf][w * 512 + i * 2048]),
          16, 0, 0);
    }
  };
  auto stageV = [&](int buf, int kv0) {
#pragma unroll
    for (int i = 0; i < 2; ++i) {
      int row = srow + i * 32;   // d index
      int sc = c16 ^ (row & 7);
      __builtin_amdgcn_global_load_lds(
          (const __attribute__((address_space(1))) void*)(Vtb + (size_t)row * NKV + kv0 + sc * 8),
          (__attribute__((address_space(3))) void*)(&lsV[buf][w * 512 + i * 2048]),
          16, 0, 0);
    }
  };

  bf16x8 qa[2];
#pragma unroll
  for (int s = 0; s < 2; ++s)
    qa[s] = *(const bf16x8*)(Qb + (size_t)lr * 512 + s * 32 + lg * 8);

  float m2 = -INFINITY;     // running max (log2 domain) for q row = q0+lr
  float lrow = 0.f;         // running denom
  f32x4v od[4] = {};        // O^T: od[n][j] -> d = n*16+lg*4+j, q = lr

  char* pwave = (char*)&plds[w][0];
  int swz = (lr & 7) << 4;

  stageK(0, 0);
  stageV(0, 0);
  stageK(1, 64);
  stageV(1, 64);
  const int NT = NKV / 64;
  for (int kt = 0; kt < NT; ++kt) {
    // t's 4 loads done; t+1's 4 may stay in flight (except last iter: drain)
    if (kt < NT - 1) {
      asm volatile("s_waitcnt vmcnt(4)" ::: "memory");
    } else {
      asm volatile("s_waitcnt vmcnt(0)" ::: "memory");
    }
    __builtin_amdgcn_s_barrier();
    __builtin_amdgcn_sched_barrier(0);
    if (kt + 2 < NT) {
      int b2 = (kt + 2) % 3;
      stageK(b2, (kt + 2) * 64);
      stageV(b2, (kt + 2) * 64);
    }
    int bi = kt % 3;
    const u16* lk = lsK[bi];
    const u16* lv = lsV[bi];

    // S^T = K Q^T: A = K-frag, B = Q-frag
    f32x4v sfr[4] = {};
    __builtin_amdgcn_s_setprio(1);
#pragma unroll
    for (int sk = 0; sk < 2; ++sk)
#pragma unroll
      for (int n = 0; n < 4; ++n) {
        bf16x8 kb = *(const bf16x8*)&lk[(n * 16 + lr) * 64 + ((sk * 4 + lg) ^ (lr & 7)) * 8];
        sfr[n] = __builtin_amdgcn_mfma_f32_16x16x32_bf16(kb, qa[sk], sfr[n], 0, 0, 0);
      }
    __builtin_amdgcn_s_setprio(0);

    // lane-local max over 16 kv values (log2 domain)
    float pm = fmaxf(fmaxf(fmaxf(sfr[0][0], sfr[0][1]), fmaxf(sfr[0][2], sfr[0][3])),
                     fmaxf(fmaxf(sfr[1][0], sfr[1][1]), fmaxf(sfr[1][2], sfr[1][3])));
    float pm2 = fmaxf(fmaxf(fmaxf(sfr[2][0], sfr[2][1]), fmaxf(sfr[2][2], sfr[2][3])),
                      fmaxf(fmaxf(sfr[3][0], sfr[3][1]), fmaxf(sfr[3][2], sfr[3][3])));
    pm = fmaxf(pm, pm2) * scale2;
    pm = fmaxf(pm, __shfl_xor(pm, 16, 64));
    pm = fmaxf(pm, __shfl_xor(pm, 32, 64));

    // exact-skip rescale
    if (__any(pm > m2)) {
      float mn = fmaxf(m2, pm);
      float alpha = __builtin_amdgcn_exp2f(m2 - mn);
      m2 = mn;
      lrow *= alpha;
#pragma unroll
      for (int n = 0; n < 4; ++n)
#pragma unroll
        for (int j = 0; j < 4; ++j)
          od[n][j] *= alpha;
    }

    float p[4][4];
    float rs = 0.f;
#pragma unroll
    for (int n = 0; n < 4; ++n)
#pragma unroll
      for (int j = 0; j < 4; ++j) {
        float e = __builtin_amdgcn_exp2f(fmaf(sfr[n][j], scale2, -m2));
        p[n][j] = e;
        rs += e;
      }
    rs += __shfl_xor(rs, 16, 64);
    rs += __shfl_xor(rs, 32, 64);
    lrow += rs;

    // P[q=lr][kv] -> LDS, 4x ds_write_b64, swizzled (cvt_pk pairs)
#pragma unroll
    for (int n = 0; n < 4; ++n) {
      ushort4 pw;
      pw.x = f2bf_c(p[n][0]); pw.y = f2bf_c(p[n][1]);
      pw.z = f2bf_c(p[n][2]); pw.w = f2bf_c(p[n][3]);
      *(ushort4*)(pwave + lr * 128 + ((n * 32 + lg * 8) ^ swz)) = pw;
    }

    // O^T += V^T P^T: A = V^T-frag, B = P^T from plds
    __builtin_amdgcn_s_setprio(1);
#pragma unroll
    for (int sk = 0; sk < 2; ++sk) {
      bf16x8 pa = *(const bf16x8*)(pwave + lr * 128 + ((sk * 64 + lg * 16) ^ swz));
#pragma unroll
      for (int n = 0; n < 4; ++n) {
        bf16x8 vb = *(const bf16x8*)&lv[(n * 16 + lr) * 64 + ((sk * 4 + lg) ^ (lr & 7)) * 8];
        od[n] = __builtin_amdgcn_mfma_f32_16x16x32_bf16(vb, pa, od[n], 0, 0, 0);
      }
    }
    __builtin_amdgcn_s_setprio(0);
  }

  float rl = 1.0f / lrow;
  u16* aob = ao + ((size_t)b * NQ + q0 + lr) * 512 + h * HD + lg * 4;
#pragma unroll
  for (int n = 0; n < 4; ++n) {
    ushort4 o;
    o.x = f2bf_c(od[n][0] * rl); o.y = f2bf_c(od[n][1] * rl);
    o.z = f2bf_c(od[n][2] * rl); o.w = f2bf_c(od[n][3] * rl);
    *(ushort4*)(aob + n * 16) = o;
  }
}

// ---------------- launch ----------------
extern "C" void kernel_launch(void* const* d_in, const int* in_sizes, int n_in,
                              void* d_out, int out_size, void* d_ws, size_t ws_size,
                              hipStream_t stream) {
  const float* q    = (const float*)d_in[0];
  const float* kv   = (const float*)d_in[1];
  const float* Wqkv = (const float*)d_in[2];
  const float* bqkv = (const float*)d_in[3];
  const float* Wout = (const float*)d_in[4];
  const float* bout = (const float*)d_in[5];
  float* out = (float*)d_out;
  uint8_t* ws = (uint8_t*)d_ws;

  u16* qf  = (u16*)(ws + 0);            // 4 MB  (B*NQ, 512) bf16
  u16* kvf = (u16*)(ws + (4u << 20));   // 8 MB  (B*NKV, 512) bf16
  u16* wq  = (u16*)(ws + (12u << 20));  // 1.5MB Wqkv bf16 (1536,512)
  u16* wo  = (u16*)(ws + (14u << 20));  // 0.5MB Wout bf16 (512,512)
  u16* qhb = (u16*)(ws + (15u << 20));  // 4 MB  (B*NQ, 512)
  u16* khv = (u16*)(ws + (19u << 20));  // 16 MB (B*NKV, 1024) K|V
  u16* vt  = (u16*)(ws + (35u << 20));  // 8 MB  (B*8*64, NKV)
  u16* ao  = (u16*)(ws + (43u << 20));  // 4 MB  (B*NQ, 512)

  dim3 blk256(256), blkT(32, 8);

  cvt_w<<<dim3((1536 * 512 + 255) / 256), blk256, 0, stream>>>(Wqkv, wq, 1536 * 512);
  cvt_w<<<dim3((512 * 512 + 255) / 256), blk256, 0, stream>>>(Wout, wo, 512 * 512);
  pack_cvt<<<dim3(NQ / 32, CDIM / 32, BATCH), blkT, 0, stream>>>(q, qf, CDIM, NQ);
  pack_cvt<<<dim3(NKV / 32, CDIM / 32, BATCH), blkT, 0, stream>>>(kv, kvf, CDIM, NKV);

  gemm_bt<0><<<dim3(BATCH * NQ / 128, 512 / 128), blk256, 0, stream>>>(
      qf, wq, bqkv, qhb, BATCH * NQ, 512, 512, 512);
  gemm_bt<0><<<dim3(BATCH * NKV / 128, 1024 / 128), blk256, 0, stream>>>(
      kvf, wq + 512 * 512, bqkv + 512, khv, BATCH * NKV, 1024, 512, 1024);

  transpose_vh<<<dim3(NKV / 32, HD / 32, BATCH * NH), blkT, 0, stream>>>(khv, vt);

  attn_fwd<<<dim3(BATCH * NH, NQ / 64), blk256, 0, stream>>>(qhb, khv, vt, ao);

  // out projection fused with NHWC->NCHW transpose, writes d_out directly
  gemm_bt<2><<<dim3(BATCH * NQ / 128, 512 / 128), blk256, 0, stream>>>(
      ao, wo, bout, out, BATCH * NQ, 512, 512, 512);
}